// Round 1
// baseline (1225.775 us; speedup 1.0000x reference)
//
#include <hip/hip_runtime.h>
#include <math.h>

#define HW2 (256*256)
#define HW1 (128*128)

// ---------------------------------------------------------------------------
// Repack conv weights OIHW (Cout,Cin,3,3) -> (Cin*9, Cout) so the inner
// COUT_TILE FMA loop reads contiguous (uniform -> scalar) weights.
// ---------------------------------------------------------------------------
__global__ __launch_bounds__(256)
void repack_w(const float* __restrict__ w, float* __restrict__ wt,
              int Cout, int Cin) {
    int idx = blockIdx.x * 256 + threadIdx.x;
    int total = Cout * Cin * 9;
    if (idx >= total) return;
    int o   = idx / (Cin * 9);
    int rem = idx - o * (Cin * 9);     // = ci*9 + t
    wt[rem * Cout + o] = w[idx];
}

// ---------------------------------------------------------------------------
// Tiled direct conv3x3, pad=1. Block = 256 threads = 16x16 output pixels.
// Each thread accumulates COUT_TILE output channels in registers.
// Input channels staged in LDS in chunks of CI_CHUNK.
// Weights: repacked (ci*9, co) layout, uniform address -> scalar loads.
// ---------------------------------------------------------------------------
template<int C_IN, int COUT_TILE, bool RELU, bool HAS_SKIP, bool CONCAT2>
__global__ __launch_bounds__(256)
void conv3x3(const float* __restrict__ in, const float* __restrict__ in2,
             const float* __restrict__ wt, const float* __restrict__ bias,
             const float* __restrict__ skip, float* __restrict__ out,
             int H, int W, int C_out) {
    constexpr int CI_CHUNK = 16;
    __shared__ float lds[CI_CHUNK * 18 * 18];

    int tid = threadIdx.x;
    int tx = tid & 15, ty = tid >> 4;
    int x0 = blockIdx.x * 16, y0 = blockIdx.y * 16;
    int zz = blockIdx.z;
    int n_co_tiles = C_out / COUT_TILE;
    int b   = zz / n_co_tiles;
    int co0 = (zz - b * n_co_tiles) * COUT_TILE;
    int x = x0 + tx, y = y0 + ty;

    float acc[COUT_TILE];
#pragma unroll
    for (int i = 0; i < COUT_TILE; ++i) acc[i] = 0.f;

    for (int c0 = 0; c0 < C_IN; c0 += CI_CHUNK) {
        __syncthreads();
        // stage CI_CHUNK channels of the 18x18 halo tile
        for (int idx = tid; idx < CI_CHUNK * 324; idx += 256) {
            int c   = idx / 324;
            int rem = idx - c * 324;
            int yy  = rem / 18;
            int xx  = rem - yy * 18;
            int gy = y0 + yy - 1, gx = x0 + xx - 1;
            float v = 0.f;
            if (gy >= 0 && gy < H && gx >= 0 && gx < W) {
                int ci = c0 + c;
                const float* src;
                if (CONCAT2) {
                    const int CH = C_IN / 2;
                    if (ci < CH) src = in  + ((size_t)(b * CH + ci) * H + gy) * W + gx;
                    else         src = in2 + ((size_t)(b * CH + (ci - CH)) * H + gy) * W + gx;
                } else {
                    src = in + ((size_t)(b * C_IN + ci) * H + gy) * W + gx;
                }
                v = *src;
            }
            lds[idx] = v;
        }
        __syncthreads();

        for (int c = 0; c < CI_CHUNK; ++c) {
#pragma unroll
            for (int t = 0; t < 9; ++t) {
                int ky = t / 3, kx = t - ky * 3;
                float xv = lds[c * 324 + (ty + ky) * 18 + (tx + kx)];
                const float* wrow = wt + ((size_t)(c0 + c) * 9 + t) * C_out + co0;
#pragma unroll
                for (int co = 0; co < COUT_TILE; ++co)
                    acc[co] = fmaf(wrow[co], xv, acc[co]);
            }
        }
    }

#pragma unroll
    for (int co = 0; co < COUT_TILE; ++co) {
        float v = acc[co] + bias[co0 + co];
        if (RELU) v = v > 0.f ? v : 0.f;
        size_t oidx = ((size_t)(b * C_out + co0 + co) * H + y) * W + x;
        if (HAS_SKIP) v += skip[oidx];
        out[oidx] = v;
    }
}

// ---------------------------------------------------------------------------
// Fused dk/gk branches: per pixel, 1x1 (64->64, ReLU) -> 1x1 (64->9),
// softmax over 9; blend with weight_map; tanh; /aff; L1-normalize.
// One thread per pixel; 64 input channels held in VGPRs; weights scalar.
// ---------------------------------------------------------------------------
__global__ __launch_bounds__(256)
void kernels_fuse(const float* __restrict__ depth, const float* __restrict__ guide,
                  const float* __restrict__ wmap,
                  const float* __restrict__ dk_w1, const float* __restrict__ dk_b1,
                  const float* __restrict__ dk_w2, const float* __restrict__ dk_b2,
                  const float* __restrict__ gk_w1, const float* __restrict__ gk_b1,
                  const float* __restrict__ gk_w2, const float* __restrict__ gk_b2,
                  const float* __restrict__ aff, float* __restrict__ fuse_out) {
    int p = blockIdx.x * 256 + threadIdx.x;   // [0, B*HW2)
    int b   = p / HW2;
    int rem = p - b * HW2;

    float xv[64];
    float dk9[9], gk9[9];

    // ---- depth branch ----
    {
        const float* src = depth + (size_t)b * 64 * HW2 + rem;
#pragma unroll
        for (int c = 0; c < 64; ++c) xv[c] = src[(size_t)c * HW2];
#pragma unroll
        for (int j = 0; j < 9; ++j) dk9[j] = dk_b2[j];
        for (int h = 0; h < 64; ++h) {
            float a = dk_b1[h];
#pragma unroll
            for (int c = 0; c < 64; ++c) a = fmaf(dk_w1[h * 64 + c], xv[c], a);
            a = a > 0.f ? a : 0.f;
#pragma unroll
            for (int j = 0; j < 9; ++j) dk9[j] = fmaf(dk_w2[j * 64 + h], a, dk9[j]);
        }
        float m = dk9[0];
#pragma unroll
        for (int j = 1; j < 9; ++j) m = fmaxf(m, dk9[j]);
        float s = 0.f;
#pragma unroll
        for (int j = 0; j < 9; ++j) { dk9[j] = __expf(dk9[j] - m); s += dk9[j]; }
        float inv = 1.f / s;
#pragma unroll
        for (int j = 0; j < 9; ++j) dk9[j] *= inv;
    }

    // ---- guide branch ----
    {
        const float* src = guide + (size_t)b * 64 * HW2 + rem;
#pragma unroll
        for (int c = 0; c < 64; ++c) xv[c] = src[(size_t)c * HW2];
#pragma unroll
        for (int j = 0; j < 9; ++j) gk9[j] = gk_b2[j];
        for (int h = 0; h < 64; ++h) {
            float a = gk_b1[h];
#pragma unroll
            for (int c = 0; c < 64; ++c) a = fmaf(gk_w1[h * 64 + c], xv[c], a);
            a = a > 0.f ? a : 0.f;
#pragma unroll
            for (int j = 0; j < 9; ++j) gk9[j] = fmaf(gk_w2[j * 64 + h], a, gk9[j]);
        }
        float m = gk9[0];
#pragma unroll
        for (int j = 1; j < 9; ++j) m = fmaxf(m, gk9[j]);
        float s = 0.f;
#pragma unroll
        for (int j = 0; j < 9; ++j) { gk9[j] = __expf(gk9[j] - m); s += gk9[j]; }
        float inv = 1.f / s;
#pragma unroll
        for (int j = 0; j < 9; ++j) gk9[j] *= inv;
    }

    // ---- blend + tanh + L1 norm ----
    float wm = wmap[p];
    float av = aff[0] + 1e-8f;
    float inv_av = 1.f / av;
    float f[9];
    float s = 0.f;
#pragma unroll
    for (int j = 0; j < 9; ++j) {
        float v = wm * dk9[j] + (1.f - wm) * gk9[j];
        v = tanhf(v) * inv_av;
        f[j] = v;
        s += fabsf(v);
    }
    float ksum = s + 1e-4f;
    if (ksum < 1.f) ksum = 1.f;
    float invk = 1.f / ksum;
#pragma unroll
    for (int j = 0; j < 9; ++j)
        fuse_out[((size_t)b * 9 + j) * HW2 + rem] = f[j] * invk;
}

// ---------------------------------------------------------------------------
// Bilinear 2x upsample, half-pixel centers, edge clamp (== jax renormalized
// edge weights). in: (B,64,128,128) -> out: (B,64,256,256)
// ---------------------------------------------------------------------------
__global__ __launch_bounds__(256)
void upsample2x(const float* __restrict__ in, float* __restrict__ out) {
    int idx = blockIdx.x * 256 + threadIdx.x;   // flat over B*64*256*256
    int x  = idx & 255;
    int y  = (idx >> 8) & 255;
    int bc = idx >> 16;

    int ylo, yhi; float wylo, wyhi;
    if (y & 1) { ylo = y >> 1; yhi = ylo + 1; if (yhi > 127) yhi = 127; wylo = 0.75f; wyhi = 0.25f; }
    else       { yhi = y >> 1; ylo = yhi - 1; if (ylo < 0)   ylo = 0;   wyhi = 0.75f; wylo = 0.25f; }
    int xlo, xhi; float wxlo, wxhi;
    if (x & 1) { xlo = x >> 1; xhi = xlo + 1; if (xhi > 127) xhi = 127; wxlo = 0.75f; wxhi = 0.25f; }
    else       { xhi = x >> 1; xlo = xhi - 1; if (xlo < 0)   xlo = 0;   wxhi = 0.75f; wxlo = 0.25f; }

    const float* src = in + (size_t)bc * HW1;
    float v = wylo * (wxlo * src[ylo * 128 + xlo] + wxhi * src[ylo * 128 + xhi])
            + wyhi * (wxlo * src[yhi * 128 + xlo] + wxhi * src[yhi * 128 + xhi]);
    out[idx] = v;
}

// ---------------------------------------------------------------------------
// Final: out[b,c,h,w] = sum_t fuse[b,t,h,w] * up[b,c, h+(ty-1)*2, w+(tx-1)*2]
// (zero outside -- unfold's zero padding).
// ---------------------------------------------------------------------------
__global__ __launch_bounds__(256)
void fuse_apply(const float* __restrict__ fuse, const float* __restrict__ up,
                float* __restrict__ out) {
    int idx = blockIdx.x * 256 + threadIdx.x;   // flat over B*64*256*256
    int x  = idx & 255;
    int y  = (idx >> 8) & 255;
    int bc = idx >> 16;
    int b  = bc >> 6;

    const float* f = fuse + (size_t)b * 9 * HW2 + y * 256 + x;
    const float* u = up + (size_t)bc * HW2;
    float acc = 0.f;
#pragma unroll
    for (int t = 0; t < 9; ++t) {
        int dy = (t / 3 - 1) * 2;
        int dx = (t % 3 - 1) * 2;
        int yy = y + dy, xx = x + dx;
        if (yy >= 0 && yy < 256 && xx >= 0 && xx < 256)
            acc = fmaf(f[(size_t)t * HW2], u[yy * 256 + xx], acc);
    }
    out[idx] = acc;
}

// ---------------------------------------------------------------------------
extern "C" void kernel_launch(void* const* d_in, const int* in_sizes, int n_in,
                              void* d_out, int out_size, void* d_ws, size_t ws_size,
                              hipStream_t stream) {
    const float* depth  = (const float*)d_in[0];
    const float* guide  = (const float*)d_in[1];
    const float* inputs = (const float*)d_in[2];
    const float* dk_w1  = (const float*)d_in[3];
    const float* dk_b1  = (const float*)d_in[4];
    const float* dk_w2  = (const float*)d_in[5];
    const float* dk_b2  = (const float*)d_in[6];
    const float* gk_w1  = (const float*)d_in[7];
    const float* gk_b1  = (const float*)d_in[8];
    const float* gk_w2  = (const float*)d_in[9];
    const float* gk_b2  = (const float*)d_in[10];
    const float* wn_w1  = (const float*)d_in[11];
    const float* wn_b1  = (const float*)d_in[12];
    const float* wn_w2  = (const float*)d_in[13];
    const float* wn_b2  = (const float*)d_in[14];
    const float* wn_w3  = (const float*)d_in[15];
    const float* wn_b3  = (const float*)d_in[16];
    const float* rb_w   = (const float*)d_in[17];
    const float* rb_b   = (const float*)d_in[18];
    const float* aff    = (const float*)d_in[19];
    float* out = (float*)d_out;

    // workspace layout (floats)
    float* ws = (float*)d_ws;
    size_t off = 0;
    float* bufA   = ws + off; off += 8388608;   // wm1, later reused for upsample
    float* bufB   = ws + off; off += 8388608;   // wm2
    float* wmap   = ws + off; off += 131072;    // weight_map (B,1,256,256)
    float* fuse   = ws + off; off += 1179648;   // (B,9,256,256)
    float* r0     = ws + off; off += 2097152;   // residual temps (B,64,128,128)
    float* r1     = ws + off; off += 2097152;
    float* r2     = ws + off; off += 2097152;
    float* wt_wn1 = ws + off; off += 73728;     // repacked weights
    float* wt_wn2 = ws + off; off += 36864;
    float* wt_wn3 = ws + off; off += 576;
    float* wt_rb  = ws + off; off += 147456;    // 4 x 36864

    // ---- repack all conv3x3 weights to (ci*9, co) ----
    repack_w<<<(73728 + 255) / 256, 256, 0, stream>>>(wn_w1, wt_wn1, 64, 128);
    repack_w<<<(36864 + 255) / 256, 256, 0, stream>>>(wn_w2, wt_wn2, 64, 64);
    repack_w<<<(576   + 255) / 256, 256, 0, stream>>>(wn_w3, wt_wn3, 1, 64);
    for (int s = 0; s < 4; ++s)
        repack_w<<<(36864 + 255) / 256, 256, 0, stream>>>(rb_w + s * 36864, wt_rb + s * 36864, 64, 64);

    // ---- weight-map trunk (256x256) ----
    conv3x3<128, 16, true,  false, true ><<<dim3(16, 16, 8), 256, 0, stream>>>(
        depth, guide, wt_wn1, wn_b1, nullptr, bufA, 256, 256, 64);
    conv3x3< 64, 16, true,  false, false><<<dim3(16, 16, 8), 256, 0, stream>>>(
        bufA, nullptr, wt_wn2, wn_b2, nullptr, bufB, 256, 256, 64);
    conv3x3< 64,  1, false, false, false><<<dim3(16, 16, 2), 256, 0, stream>>>(
        bufB, nullptr, wt_wn3, wn_b3, nullptr, wmap, 256, 256, 1);

    // ---- dk/gk branches + blend + tanh + normalize -> fuse ----
    kernels_fuse<<<512, 256, 0, stream>>>(depth, guide, wmap,
                                          dk_w1, dk_b1, dk_w2, dk_b2,
                                          gk_w1, gk_b1, gk_w2, gk_b2,
                                          aff, fuse);

    // ---- residual stack on low-res inputs (128x128) ----
    conv3x3<64, 16, true,  false, false><<<dim3(8, 8, 8), 256, 0, stream>>>(
        inputs, nullptr, wt_rb + 0 * 36864, rb_b + 0 * 64, nullptr, r0, 128, 128, 64);
    conv3x3<64, 16, false, true,  false><<<dim3(8, 8, 8), 256, 0, stream>>>(
        r0, nullptr, wt_rb + 1 * 36864, rb_b + 1 * 64, inputs, r1, 128, 128, 64);
    conv3x3<64, 16, true,  false, false><<<dim3(8, 8, 8), 256, 0, stream>>>(
        r1, nullptr, wt_rb + 2 * 36864, rb_b + 2 * 64, nullptr, r0, 128, 128, 64);
    conv3x3<64, 16, false, true,  false><<<dim3(8, 8, 8), 256, 0, stream>>>(
        r0, nullptr, wt_rb + 3 * 36864, rb_b + 3 * 64, r1, r2, 128, 128, 64);

    // ---- upsample + 9-tap dilated gather ----
    upsample2x<<<32768, 256, 0, stream>>>(r2, bufA);
    fuse_apply<<<32768, 256, 0, stream>>>(fuse, bufA, out);
}

// Round 2
// 695.985 us; speedup vs baseline: 1.7612x; 1.7612x over previous
//
#include <hip/hip_runtime.h>
#include <hip/hip_bf16.h>
#include <math.h>

#define HW2 (256*256)
#define HW1 (128*128)

typedef __attribute__((ext_vector_type(8))) short short8;
typedef __attribute__((ext_vector_type(4))) float floatx4;

// ---------------------------------------------------------------------------
// Repack conv weights OIHW fp32 (Cout=64, Cin, 3,3) -> bf16 [ci/32][t][co][ci%32]
// so per-chunk weight slices are contiguous 36KB blocks and B-fragments are
// contiguous 16B per lane.
// ---------------------------------------------------------------------------
__global__ __launch_bounds__(256)
void repack_w_bf16(const float* __restrict__ w, ushort* __restrict__ wt, int Cin) {
    int idx = blockIdx.x * 256 + threadIdx.x;
    int total = 64 * Cin * 9;
    if (idx >= total) return;
    int o   = idx / (Cin * 9);
    int rem = idx - o * (Cin * 9);
    int ci  = rem / 9;
    int t   = rem - ci * 9;
    int cc = ci >> 5, cl = ci & 31;
    __hip_bfloat16 bv = __float2bfloat16(w[idx]);
    wt[(((size_t)cc * 9 + t) * 64 + o) * 32 + cl] = *(ushort*)&bv;
}

// ---------------------------------------------------------------------------
// Implicit-GEMM conv3x3 (pad=1) via bf16 MFMA, Cout=64 fixed.
// Block: 16(x) x 8(y) pixel tile, 256 threads = 4 waves.
// Wave w computes rows {2w, 2w+1} (2 M-tiles of 16 px) x all 64 out channels
// (4 N-tiles) with mfma_f32_16x16x32_bf16; K = Cin*9, chunked by 32 channels.
// A-frag: lane holds 8 contiguous channels at pixel (ml) -> ds_read_b128.
// B-frag: lane holds 8 contiguous channels at out-ch (ml) -> ds_read_b128.
// C/D: col(lane&15)=out-ch, row(q*4+reg)=pixel x -> float4 global store.
// ---------------------------------------------------------------------------
template<int C_IN, bool RELU, bool HAS_SKIP, bool CONCAT2>
__global__ __launch_bounds__(256)
void conv3x3_mfma(const float* __restrict__ in, const float* __restrict__ in2,
                  const ushort* __restrict__ wt, const float* __restrict__ bias,
                  const float* __restrict__ skip, float* __restrict__ out,
                  int H, int W) {
    constexpr int NCHUNK = C_IN / 32;
    __shared__ __align__(16) ushort a_tile[10 * 18 * 32];   // [y][x][ci] bf16
    __shared__ __align__(16) ushort w_tile[9 * 64 * 32];    // [t][co][ci] bf16

    int tid  = threadIdx.x;
    int wv   = tid >> 6;
    int lane = tid & 63;
    int ml   = lane & 15;
    int q    = lane >> 4;

    int x0 = blockIdx.x * 16;
    int y0 = blockIdx.y * 8;
    int b  = blockIdx.z;

    floatx4 acc[2][4];
#pragma unroll
    for (int r = 0; r < 2; ++r)
#pragma unroll
        for (int n = 0; n < 4; ++n) acc[r][n] = (floatx4){0.f, 0.f, 0.f, 0.f};

    for (int cc = 0; cc < NCHUNK; ++cc) {
        int ci0 = cc * 32;
        const float* src;
        int cbase, csz;
        if (CONCAT2) {
            constexpr int CH = C_IN / 2;
            if (ci0 < CH) { src = in;  cbase = ci0;      }
            else          { src = in2; cbase = ci0 - CH; }
            csz = CH;
        } else { src = in; cbase = ci0; csz = C_IN; }

        __syncthreads();
        // stage input halo tile: 10 x 18 x 32 channels, fp32 -> bf16
        for (int idx = tid; idx < 5760; idx += 256) {
            int ci = idx / 180;
            int p  = idx - ci * 180;
            int yy = p / 18;
            int xx = p - yy * 18;
            int gy = y0 + yy - 1, gx = x0 + xx - 1;
            float v = 0.f;
            if ((unsigned)gy < (unsigned)H && (unsigned)gx < (unsigned)W)
                v = src[((size_t)(b * csz + cbase + ci) * H + gy) * W + gx];
            __hip_bfloat16 bv = __float2bfloat16(v);
            a_tile[(yy * 18 + xx) * 32 + ci] = *(ushort*)&bv;
        }
        // stage weight slice: contiguous 18432 ushorts
        {
            const uint4* wsrc = (const uint4*)(wt + (size_t)cc * 18432);
            uint4* wdst = (uint4*)w_tile;
            for (int idx = tid; idx < 2304; idx += 256) wdst[idx] = wsrc[idx];
        }
        __syncthreads();

#pragma unroll
        for (int t = 0; t < 9; ++t) {
            int dy = t / 3, dx = t - dy * 3;
            short8 afr[2], bfr[4];
#pragma unroll
            for (int r = 0; r < 2; ++r) {
                int yy = 2 * wv + r + dy;
                int xx = ml + dx;
                afr[r] = *(const short8*)&a_tile[(yy * 18 + xx) * 32 + q * 8];
            }
#pragma unroll
            for (int n = 0; n < 4; ++n)
                bfr[n] = *(const short8*)&w_tile[(t * 64 + n * 16 + ml) * 32 + q * 8];
#pragma unroll
            for (int r = 0; r < 2; ++r)
#pragma unroll
                for (int n = 0; n < 4; ++n)
                    acc[r][n] = __builtin_amdgcn_mfma_f32_16x16x32_bf16(
                        afr[r], bfr[n], acc[r][n], 0, 0, 0);
        }
    }

    // epilogue: lane holds 4 consecutive x at (row y, channel ch) -> float4
#pragma unroll
    for (int r = 0; r < 2; ++r) {
        int y = y0 + 2 * wv + r;
#pragma unroll
        for (int n = 0; n < 4; ++n) {
            int ch = n * 16 + ml;
            float bs = bias[ch];
            size_t base = ((size_t)(b * 64 + ch) * H + y) * W + x0 + q * 4;
            floatx4 v = acc[r][n];
            v.x += bs; v.y += bs; v.z += bs; v.w += bs;
            if (RELU) {
                v.x = v.x > 0.f ? v.x : 0.f;
                v.y = v.y > 0.f ? v.y : 0.f;
                v.z = v.z > 0.f ? v.z : 0.f;
                v.w = v.w > 0.f ? v.w : 0.f;
            }
            if (HAS_SKIP) {
                floatx4 s = *(const floatx4*)&skip[base];
                v.x += s.x; v.y += s.y; v.z += s.z; v.w += s.w;
            }
            *(floatx4*)&out[base] = v;
        }
    }
}

// ---------------------------------------------------------------------------
// wn3: 3x3 conv 64ch -> 1ch at 256x256. Weights (576 floats) in LDS,
// one thread per output pixel, inputs read from global (L1/L2 hot).
// ---------------------------------------------------------------------------
__global__ __launch_bounds__(256)
void conv3x3_1out(const float* __restrict__ in, const float* __restrict__ w,
                  const float* __restrict__ bias, float* __restrict__ out) {
    __shared__ float wl[576];
    int tid = threadIdx.x;
    for (int i = tid; i < 576; i += 256) wl[i] = w[i];
    __syncthreads();

    int tx = tid & 15, ty = tid >> 4;
    int x = blockIdx.x * 16 + tx;
    int y = blockIdx.y * 16 + ty;
    int b = blockIdx.z;

    float acc = bias[0];
#pragma unroll
    for (int t = 0; t < 9; ++t) {
        int dy = t / 3, dx = t - dy * 3;
        int gy = y + dy - 1, gx = x + dx - 1;
        if ((unsigned)gy < 256u && (unsigned)gx < 256u) {
            const float* src = in + (size_t)b * 64 * HW2 + gy * 256 + gx;
            for (int ci = 0; ci < 64; ++ci)
                acc = fmaf(wl[ci * 9 + t], src[(size_t)ci * HW2], acc);
        }
    }
    out[(size_t)b * HW2 + y * 256 + x] = acc;
}

// ---------------------------------------------------------------------------
// Fused dk/gk branches: per pixel, 1x1 (64->64, ReLU) -> 1x1 (64->9),
// softmax over 9; blend with weight_map; tanh; /aff; L1-normalize.
// ---------------------------------------------------------------------------
__global__ __launch_bounds__(256)
void kernels_fuse(const float* __restrict__ depth, const float* __restrict__ guide,
                  const float* __restrict__ wmap,
                  const float* __restrict__ dk_w1, const float* __restrict__ dk_b1,
                  const float* __restrict__ dk_w2, const float* __restrict__ dk_b2,
                  const float* __restrict__ gk_w1, const float* __restrict__ gk_b1,
                  const float* __restrict__ gk_w2, const float* __restrict__ gk_b2,
                  const float* __restrict__ aff, float* __restrict__ fuse_out) {
    int p = blockIdx.x * 256 + threadIdx.x;   // [0, B*HW2)
    int b   = p / HW2;
    int rem = p - b * HW2;

    float xv[64];
    float dk9[9], gk9[9];

    {
        const float* src = depth + (size_t)b * 64 * HW2 + rem;
#pragma unroll
        for (int c = 0; c < 64; ++c) xv[c] = src[(size_t)c * HW2];
#pragma unroll
        for (int j = 0; j < 9; ++j) dk9[j] = dk_b2[j];
        for (int h = 0; h < 64; ++h) {
            float a = dk_b1[h];
#pragma unroll
            for (int c = 0; c < 64; ++c) a = fmaf(dk_w1[h * 64 + c], xv[c], a);
            a = a > 0.f ? a : 0.f;
#pragma unroll
            for (int j = 0; j < 9; ++j) dk9[j] = fmaf(dk_w2[j * 64 + h], a, dk9[j]);
        }
        float m = dk9[0];
#pragma unroll
        for (int j = 1; j < 9; ++j) m = fmaxf(m, dk9[j]);
        float s = 0.f;
#pragma unroll
        for (int j = 0; j < 9; ++j) { dk9[j] = __expf(dk9[j] - m); s += dk9[j]; }
        float inv = 1.f / s;
#pragma unroll
        for (int j = 0; j < 9; ++j) dk9[j] *= inv;
    }
    {
        const float* src = guide + (size_t)b * 64 * HW2 + rem;
#pragma unroll
        for (int c = 0; c < 64; ++c) xv[c] = src[(size_t)c * HW2];
#pragma unroll
        for (int j = 0; j < 9; ++j) gk9[j] = gk_b2[j];
        for (int h = 0; h < 64; ++h) {
            float a = gk_b1[h];
#pragma unroll
            for (int c = 0; c < 64; ++c) a = fmaf(gk_w1[h * 64 + c], xv[c], a);
            a = a > 0.f ? a : 0.f;
#pragma unroll
            for (int j = 0; j < 9; ++j) gk9[j] = fmaf(gk_w2[j * 64 + h], a, gk9[j]);
        }
        float m = gk9[0];
#pragma unroll
        for (int j = 1; j < 9; ++j) m = fmaxf(m, gk9[j]);
        float s = 0.f;
#pragma unroll
        for (int j = 0; j < 9; ++j) { gk9[j] = __expf(gk9[j] - m); s += gk9[j]; }
        float inv = 1.f / s;
#pragma unroll
        for (int j = 0; j < 9; ++j) gk9[j] *= inv;
    }

    float wm = wmap[p];
    float av = aff[0] + 1e-8f;
    float inv_av = 1.f / av;
    float f[9];
    float s = 0.f;
#pragma unroll
    for (int j = 0; j < 9; ++j) {
        float v = wm * dk9[j] + (1.f - wm) * gk9[j];
        v = tanhf(v) * inv_av;
        f[j] = v;
        s += fabsf(v);
    }
    float ksum = s + 1e-4f;
    if (ksum < 1.f) ksum = 1.f;
    float invk = 1.f / ksum;
#pragma unroll
    for (int j = 0; j < 9; ++j)
        fuse_out[((size_t)b * 9 + j) * HW2 + rem] = f[j] * invk;
}

// ---------------------------------------------------------------------------
// Bilinear 2x upsample, half-pixel centers, edge clamp.
// ---------------------------------------------------------------------------
__global__ __launch_bounds__(256)
void upsample2x(const float* __restrict__ in, float* __restrict__ out) {
    int idx = blockIdx.x * 256 + threadIdx.x;
    int x  = idx & 255;
    int y  = (idx >> 8) & 255;
    int bc = idx >> 16;

    int ylo, yhi; float wylo, wyhi;
    if (y & 1) { ylo = y >> 1; yhi = ylo + 1; if (yhi > 127) yhi = 127; wylo = 0.75f; wyhi = 0.25f; }
    else       { yhi = y >> 1; ylo = yhi - 1; if (ylo < 0)   ylo = 0;   wyhi = 0.75f; wylo = 0.25f; }
    int xlo, xhi; float wxlo, wxhi;
    if (x & 1) { xlo = x >> 1; xhi = xlo + 1; if (xhi > 127) xhi = 127; wxlo = 0.75f; wxhi = 0.25f; }
    else       { xhi = x >> 1; xlo = xhi - 1; if (xlo < 0)   xlo = 0;   wxhi = 0.75f; wxlo = 0.25f; }

    const float* src = in + (size_t)bc * HW1;
    float v = wylo * (wxlo * src[ylo * 128 + xlo] + wxhi * src[ylo * 128 + xhi])
            + wyhi * (wxlo * src[yhi * 128 + xlo] + wxhi * src[yhi * 128 + xhi]);
    out[idx] = v;
}

// ---------------------------------------------------------------------------
// Final 9-tap dilated gather.
// ---------------------------------------------------------------------------
__global__ __launch_bounds__(256)
void fuse_apply(const float* __restrict__ fuse, const float* __restrict__ up,
                float* __restrict__ out) {
    int idx = blockIdx.x * 256 + threadIdx.x;
    int x  = idx & 255;
    int y  = (idx >> 8) & 255;
    int bc = idx >> 16;
    int b  = bc >> 6;

    const float* f = fuse + (size_t)b * 9 * HW2 + y * 256 + x;
    const float* u = up + (size_t)bc * HW2;
    float acc = 0.f;
#pragma unroll
    for (int t = 0; t < 9; ++t) {
        int dy = (t / 3 - 1) * 2;
        int dx = (t % 3 - 1) * 2;
        int yy = y + dy, xx = x + dx;
        if (yy >= 0 && yy < 256 && xx >= 0 && xx < 256)
            acc = fmaf(f[(size_t)t * HW2], u[yy * 256 + xx], acc);
    }
    out[idx] = acc;
}

// ---------------------------------------------------------------------------
extern "C" void kernel_launch(void* const* d_in, const int* in_sizes, int n_in,
                              void* d_out, int out_size, void* d_ws, size_t ws_size,
                              hipStream_t stream) {
    const float* depth  = (const float*)d_in[0];
    const float* guide  = (const float*)d_in[1];
    const float* inputs = (const float*)d_in[2];
    const float* dk_w1  = (const float*)d_in[3];
    const float* dk_b1  = (const float*)d_in[4];
    const float* dk_w2  = (const float*)d_in[5];
    const float* dk_b2  = (const float*)d_in[6];
    const float* gk_w1  = (const float*)d_in[7];
    const float* gk_b1  = (const float*)d_in[8];
    const float* gk_w2  = (const float*)d_in[9];
    const float* gk_b2  = (const float*)d_in[10];
    const float* wn_w1  = (const float*)d_in[11];
    const float* wn_b1  = (const float*)d_in[12];
    const float* wn_w2  = (const float*)d_in[13];
    const float* wn_b2  = (const float*)d_in[14];
    const float* wn_w3  = (const float*)d_in[15];
    const float* wn_b3  = (const float*)d_in[16];
    const float* rb_w   = (const float*)d_in[17];
    const float* rb_b   = (const float*)d_in[18];
    const float* aff    = (const float*)d_in[19];
    float* out = (float*)d_out;

    // workspace layout (float units)
    float* ws = (float*)d_ws;
    size_t off = 0;
    float* bufA   = ws + off; off += 8388608;   // (B,64,256,256), reused for upsample
    float* bufB   = ws + off; off += 8388608;
    float* wmap   = ws + off; off += 131072;
    float* fuse   = ws + off; off += 1179648;
    float* r0     = ws + off; off += 2097152;
    float* r1     = ws + off; off += 2097152;
    float* r2     = ws + off; off += 2097152;
    ushort* wt_wn1 = (ushort*)(ws + off); off += 36864;  // 73728 bf16
    ushort* wt_wn2 = (ushort*)(ws + off); off += 18432;  // 36864 bf16
    ushort* wt_rb  = (ushort*)(ws + off); off += 73728;  // 4 x 36864 bf16

    // ---- repack weights to bf16 [chunk][t][co][ci32] ----
    repack_w_bf16<<<288, 256, 0, stream>>>(wn_w1, wt_wn1, 128);
    repack_w_bf16<<<144, 256, 0, stream>>>(wn_w2, wt_wn2, 64);
    for (int s = 0; s < 4; ++s)
        repack_w_bf16<<<144, 256, 0, stream>>>(rb_w + s * 36864, wt_rb + (size_t)s * 36864, 64);

    // ---- weight-map trunk (256x256) ----
    conv3x3_mfma<128, true, false, true ><<<dim3(16, 32, 2), 256, 0, stream>>>(
        depth, guide, wt_wn1, wn_b1, nullptr, bufA, 256, 256);
    conv3x3_mfma< 64, true, false, false><<<dim3(16, 32, 2), 256, 0, stream>>>(
        bufA, nullptr, wt_wn2, wn_b2, nullptr, bufB, 256, 256);
    conv3x3_1out<<<dim3(16, 16, 2), 256, 0, stream>>>(bufB, wn_w3, wn_b3, wmap);

    // ---- dk/gk branches + blend + tanh + normalize ----
    kernels_fuse<<<512, 256, 0, stream>>>(depth, guide, wmap,
                                          dk_w1, dk_b1, dk_w2, dk_b2,
                                          gk_w1, gk_b1, gk_w2, gk_b2,
                                          aff, fuse);

    // ---- residual stack (128x128) ----
    conv3x3_mfma<64, true,  false, false><<<dim3(8, 16, 2), 256, 0, stream>>>(
        inputs, nullptr, wt_rb + 0 * 36864, rb_b + 0 * 64, nullptr, r0, 128, 128);
    conv3x3_mfma<64, false, true,  false><<<dim3(8, 16, 2), 256, 0, stream>>>(
        r0, nullptr, wt_rb + 1 * 36864, rb_b + 1 * 64, inputs, r1, 128, 128);
    conv3x3_mfma<64, true,  false, false><<<dim3(8, 16, 2), 256, 0, stream>>>(
        r1, nullptr, wt_rb + 2 * 36864, rb_b + 2 * 64, nullptr, r0, 128, 128);
    conv3x3_mfma<64, false, true,  false><<<dim3(8, 16, 2), 256, 0, stream>>>(
        r0, nullptr, wt_rb + 3 * 36864, rb_b + 3 * 64, r1, r2, 128, 128);

    // ---- upsample + 9-tap dilated gather ----
    upsample2x<<<32768, 256, 0, stream>>>(r2, bufA);
    fuse_apply<<<32768, 256, 0, stream>>>(fuse, bufA, out);
}

// Round 3
// 452.055 us; speedup vs baseline: 2.7116x; 1.5396x over previous
//
#include <hip/hip_runtime.h>
#include <hip/hip_bf16.h>
#include <math.h>

#define HW2 (256*256)
#define HW1 (128*128)

typedef __attribute__((ext_vector_type(8))) short short8;
typedef __attribute__((ext_vector_type(4))) float floatx4;

__device__ __forceinline__ float b2f(ushort u) {
    union { unsigned int i; float f; } v; v.i = ((unsigned int)u) << 16; return v.f;
}
__device__ __forceinline__ ushort f2b(float f) {
    __hip_bfloat16 h = __float2bfloat16(f); return *(ushort*)&h;
}

// ---------------------------------------------------------------------------
// Repack conv weights OIHW fp32 (Cout=64, Cin, 3,3) -> bf16 [ci/32][t][co][ci%32]
// ---------------------------------------------------------------------------
__global__ __launch_bounds__(256)
void repack_w_bf16(const float* __restrict__ w, ushort* __restrict__ wt, int Cin) {
    int idx = blockIdx.x * 256 + threadIdx.x;
    int total = 64 * Cin * 9;
    if (idx >= total) return;
    int o   = idx / (Cin * 9);
    int rem = idx - o * (Cin * 9);
    int ci  = rem / 9;
    int t   = rem - ci * 9;
    int cc = ci >> 5, cl = ci & 31;
    wt[(((size_t)cc * 9 + t) * 64 + o) * 32 + cl] = f2b(w[idx]);
}

// ---------------------------------------------------------------------------
// NCHW fp32 -> border-padded channel-chunked bf16: [b*Cc+cc][(H+2)][(W+2)][32]
// Border pixels written as zeros (conv pad=1 comes for free, no guards).
// ---------------------------------------------------------------------------
__global__ __launch_bounds__(256)
void to_chunked(const float* __restrict__ in, ushort* __restrict__ outc,
                int H, int W, int Cchunks) {
    int P = W + 2, Q = H + 2;
    int plane_px = P * Q;
    int idx = blockIdx.x * 256 + threadIdx.x;
    if (idx >= plane_px) return;
    int py = idx / P, px = idx - py * P;
    int bc = blockIdx.y;                 // b*Cchunks + cc
    int b = bc / Cchunks, cc = bc - b * Cchunks;
    ushort* dst = outc + ((size_t)bc * plane_px + idx) * 32;
    if (py == 0 || py == Q - 1 || px == 0 || px == P - 1) {
        for (int c = 0; c < 32; ++c) dst[c] = 0;
        return;
    }
    int y = py - 1, x = px - 1;
    const float* src = in + ((size_t)b * (Cchunks * 32) + cc * 32) * H * W
                          + (size_t)y * W + x;
    for (int c = 0; c < 32; ++c)
        dst[c] = f2b(src[(size_t)c * H * W]);
}

// ---------------------------------------------------------------------------
// Zero the 1-px borders of nplanes chunked planes (conv outputs never write
// borders; consumers rely on them being zero; ws is poisoned every launch).
// ---------------------------------------------------------------------------
__global__ __launch_bounds__(256)
void zero_border(ushort* __restrict__ buf, int H, int W, int nplanes) {
    int P = W + 2, Q = H + 2;
    int nb = 2 * P + 2 * H;
    int idx = blockIdx.x * 256 + threadIdx.x;
    if (idx >= nb * nplanes) return;
    int pl = idx / nb, r = idx - pl * nb;
    int py, px;
    if (r < P)          { py = 0;     px = r; }
    else if (r < 2 * P) { py = Q - 1; px = r - P; }
    else { int k = r - 2 * P; py = 1 + (k >> 1); px = (k & 1) ? P - 1 : 0; }
    ushort* dst = buf + ((size_t)pl * P * Q + (size_t)py * P + px) * 32;
    for (int c = 0; c < 32; ++c) dst[c] = 0;
}

// ---------------------------------------------------------------------------
// LDS-free, barrier-free implicit-GEMM conv3x3 (pad=1), Cout=64.
// Wave = 4 row-tiles (M=16 px each) x 4 N-tiles (64 out ch) of
// mfma_f32_16x16x32_bf16. A/B fragments are direct coalesced 16B global
// loads from the padded chunked bf16 layout (L1/L2-cached).
// blockDim = 128 or 256 (2 or 4 waves); block covers 16 x (waves*4) pixels.
// ---------------------------------------------------------------------------
template<int NCHUNK, bool RELU, bool HAS_SKIP, bool CONCAT2>
__global__ __launch_bounds__(256)
void conv3x3_reg(const ushort* __restrict__ inA, const ushort* __restrict__ inB,
                 const ushort* __restrict__ wt, const float* __restrict__ bias,
                 const ushort* __restrict__ skip, ushort* __restrict__ outc,
                 int H, int W) {
    const int P = W + 2;
    const size_t plane = (size_t)P * (H + 2) * 32;
    int tid = threadIdx.x;
    int wv = tid >> 6, lane = tid & 63, ml = lane & 15, q = lane >> 4;
    int x0 = blockIdx.x * 16;
    int rowsPerBlock = (blockDim.x >> 6) * 4;
    int yb = blockIdx.y * rowsPerBlock + wv * 4;
    int b = blockIdx.z;

    floatx4 acc[4][4];
#pragma unroll
    for (int r = 0; r < 4; ++r)
#pragma unroll
        for (int n = 0; n < 4; ++n) acc[r][n] = (floatx4){0.f, 0.f, 0.f, 0.f};

    for (int cc = 0; cc < NCHUNK; ++cc) {
        const ushort* base;
        if (CONCAT2) {
            constexpr int HC = NCHUNK / 2;
            if (cc < HC) base = inA + ((size_t)(b * HC + cc)) * plane;
            else         base = inB + ((size_t)(b * HC + cc - HC)) * plane;
        } else {
            base = inA + ((size_t)(b * NCHUNK + cc)) * plane;
        }
        const ushort* wb = wt + (size_t)cc * 18432;
#pragma unroll
        for (int t = 0; t < 9; ++t) {
            int dy = t / 3, dx = t - 3 * dy;
            short8 afr[4], bfr[4];
#pragma unroll
            for (int r = 0; r < 4; ++r)
                afr[r] = *(const short8*)&base[((size_t)(yb + r + dy) * P
                                               + (x0 + ml + dx)) * 32 + q * 8];
#pragma unroll
            for (int n = 0; n < 4; ++n)
                bfr[n] = *(const short8*)&wb[(size_t)(t * 64 + n * 16 + ml) * 32 + q * 8];
#pragma unroll
            for (int r = 0; r < 4; ++r)
#pragma unroll
                for (int n = 0; n < 4; ++n)
                    acc[r][n] = __builtin_amdgcn_mfma_f32_16x16x32_bf16(
                        afr[r], bfr[n], acc[r][n], 0, 0, 0);
        }
    }

    // epilogue: C/D col(lane&15)=out-ch, row(q*4+e)=pixel x
#pragma unroll
    for (int r = 0; r < 4; ++r) {
        int y = yb + r;
#pragma unroll
        for (int n = 0; n < 4; ++n) {
            int ch = n * 16 + ml;
            int occ = ch >> 5, ocl = ch & 31;
            float bs = bias[ch];
            size_t pbase = ((size_t)(b * 2 + occ)) * plane + ((size_t)(y + 1) * P) * 32 + ocl;
#pragma unroll
            for (int e = 0; e < 4; ++e) {
                int x = x0 + q * 4 + e;
                float v = acc[r][n][e] + bs;
                if (RELU) v = fmaxf(v, 0.f);
                if (HAS_SKIP)
                    v += b2f(skip[((size_t)(b * 2 + occ)) * plane
                                  + ((size_t)(y + 1) * P + (x + 1)) * 32 + ocl]);
                outc[pbase + (size_t)(x + 1) * 32] = f2b(v);
            }
        }
    }
}

// ---------------------------------------------------------------------------
// wn3: 3x3 conv 64ch -> 1ch at 256x256 from chunked bf16 input.
// ---------------------------------------------------------------------------
__global__ __launch_bounds__(256)
void conv3x3_1out_c(const ushort* __restrict__ inc, const float* __restrict__ w,
                    const float* __restrict__ bias, float* __restrict__ out) {
    __shared__ float wl[576];
    int tid = threadIdx.x;
    for (int i = tid; i < 576; i += 256) wl[i] = w[i];
    __syncthreads();

    int x = blockIdx.x * 16 + (tid & 15);
    int y = blockIdx.y * 16 + (tid >> 4);
    int b = blockIdx.z;
    const int P = 258;
    const size_t plane = (size_t)P * 258 * 32;

    float acc = bias[0];
    for (int cc = 0; cc < 2; ++cc) {
        const ushort* base = inc + ((size_t)(b * 2 + cc)) * plane;
#pragma unroll
        for (int t = 0; t < 9; ++t) {
            int dy = t / 3, dx = t - 3 * dy;
            const ushort* p = base + ((size_t)(y + dy) * P + (x + dx)) * 32;
            for (int c = 0; c < 32; ++c)
                acc = fmaf(wl[(cc * 32 + c) * 9 + t], b2f(p[c]), acc);
        }
    }
    out[(size_t)b * HW2 + y * 256 + x] = acc;
}

// ---------------------------------------------------------------------------
// Fused dk/gk 1x1 branches + softmax + blend + tanh + L1-norm.
// Inputs from chunked bf16 (contiguous 64B per pixel per chunk).
// ---------------------------------------------------------------------------
__global__ __launch_bounds__(256)
void kernels_fuse_c(const ushort* __restrict__ depth_c, const ushort* __restrict__ guide_c,
                    const float* __restrict__ wmap,
                    const float* __restrict__ dk_w1, const float* __restrict__ dk_b1,
                    const float* __restrict__ dk_w2, const float* __restrict__ dk_b2,
                    const float* __restrict__ gk_w1, const float* __restrict__ gk_b1,
                    const float* __restrict__ gk_w2, const float* __restrict__ gk_b2,
                    const float* __restrict__ aff, float* __restrict__ fuse_out) {
    int p = blockIdx.x * 256 + threadIdx.x;    // [0, B*HW2)
    int b = p >> 16;
    int rem = p & 65535;
    int y = rem >> 8, x = rem & 255;
    const int P = 258;
    const size_t plane = (size_t)P * 258 * 32;
    size_t poff = ((size_t)(y + 1) * P + (x + 1)) * 32;

    float xv[64];
    float dk9[9], gk9[9];

    {
        const ushort* s0 = depth_c + (size_t)(b * 2) * plane + poff;
#pragma unroll
        for (int c = 0; c < 32; ++c) xv[c] = b2f(s0[c]);
        const ushort* s1 = s0 + plane;
#pragma unroll
        for (int c = 0; c < 32; ++c) xv[32 + c] = b2f(s1[c]);
#pragma unroll
        for (int j = 0; j < 9; ++j) dk9[j] = dk_b2[j];
        for (int h = 0; h < 64; ++h) {
            float a = dk_b1[h];
#pragma unroll
            for (int c = 0; c < 64; ++c) a = fmaf(dk_w1[h * 64 + c], xv[c], a);
            a = a > 0.f ? a : 0.f;
#pragma unroll
            for (int j = 0; j < 9; ++j) dk9[j] = fmaf(dk_w2[j * 64 + h], a, dk9[j]);
        }
        float m = dk9[0];
#pragma unroll
        for (int j = 1; j < 9; ++j) m = fmaxf(m, dk9[j]);
        float s = 0.f;
#pragma unroll
        for (int j = 0; j < 9; ++j) { dk9[j] = __expf(dk9[j] - m); s += dk9[j]; }
        float inv = 1.f / s;
#pragma unroll
        for (int j = 0; j < 9; ++j) dk9[j] *= inv;
    }
    {
        const ushort* s0 = guide_c + (size_t)(b * 2) * plane + poff;
#pragma unroll
        for (int c = 0; c < 32; ++c) xv[c] = b2f(s0[c]);
        const ushort* s1 = s0 + plane;
#pragma unroll
        for (int c = 0; c < 32; ++c) xv[32 + c] = b2f(s1[c]);
#pragma unroll
        for (int j = 0; j < 9; ++j) gk9[j] = gk_b2[j];
        for (int h = 0; h < 64; ++h) {
            float a = gk_b1[h];
#pragma unroll
            for (int c = 0; c < 64; ++c) a = fmaf(gk_w1[h * 64 + c], xv[c], a);
            a = a > 0.f ? a : 0.f;
#pragma unroll
            for (int j = 0; j < 9; ++j) gk9[j] = fmaf(gk_w2[j * 64 + h], a, gk9[j]);
        }
        float m = gk9[0];
#pragma unroll
        for (int j = 1; j < 9; ++j) m = fmaxf(m, gk9[j]);
        float s = 0.f;
#pragma unroll
        for (int j = 0; j < 9; ++j) { gk9[j] = __expf(gk9[j] - m); s += gk9[j]; }
        float inv = 1.f / s;
#pragma unroll
        for (int j = 0; j < 9; ++j) gk9[j] *= inv;
    }

    float wm = wmap[p];
    float inv_av = 1.f / (aff[0] + 1e-8f);
    float f[9];
    float s = 0.f;
#pragma unroll
    for (int j = 0; j < 9; ++j) {
        float v = wm * dk9[j] + (1.f - wm) * gk9[j];
        v = tanhf(v) * inv_av;
        f[j] = v;
        s += fabsf(v);
    }
    float ksum = s + 1e-4f;
    if (ksum < 1.f) ksum = 1.f;
    float invk = 1.f / ksum;
#pragma unroll
    for (int j = 0; j < 9; ++j)
        fuse_out[((size_t)b * 9 + j) * HW2 + rem] = f[j] * invk;
}

// ---------------------------------------------------------------------------
// Bilinear 2x upsample: chunked bf16 (130-pad1) -> chunked bf16 (260-pad2).
// Writes its own zero borders (pad=2 for the dilated gather).
// ---------------------------------------------------------------------------
__global__ __launch_bounds__(256)
void upsample2x_c(const ushort* __restrict__ inc, ushort* __restrict__ outc) {
    int idx = blockIdx.x * 256 + threadIdx.x;   // over 260*260
    if (idx >= 260 * 260) return;
    int py = idx / 260, px = idx - py * 260;
    int pl = blockIdx.y;                        // b*2+cc
    ushort* dst = outc + ((size_t)pl * 260 * 260 + idx) * 32;
    if (py < 2 || py >= 258 || px < 2 || px >= 258) {
        for (int c = 0; c < 32; ++c) dst[c] = 0;
        return;
    }
    int y = py - 2, x = px - 2;

    int ylo, yhi; float wylo, wyhi;
    if (y & 1) { ylo = y >> 1; yhi = ylo + 1; if (yhi > 127) yhi = 127; wylo = 0.75f; wyhi = 0.25f; }
    else       { yhi = y >> 1; ylo = yhi - 1; if (ylo < 0)   ylo = 0;   wyhi = 0.75f; wylo = 0.25f; }
    int xlo, xhi; float wxlo, wxhi;
    if (x & 1) { xlo = x >> 1; xhi = xlo + 1; if (xhi > 127) xhi = 127; wxlo = 0.75f; wxhi = 0.25f; }
    else       { xhi = x >> 1; xlo = xhi - 1; if (xlo < 0)   xlo = 0;   wxhi = 0.75f; wxlo = 0.25f; }

    const ushort* base = inc + (size_t)pl * 130 * 130 * 32;
    const ushort* p00 = base + ((size_t)(ylo + 1) * 130 + (xlo + 1)) * 32;
    const ushort* p01 = base + ((size_t)(ylo + 1) * 130 + (xhi + 1)) * 32;
    const ushort* p10 = base + ((size_t)(yhi + 1) * 130 + (xlo + 1)) * 32;
    const ushort* p11 = base + ((size_t)(yhi + 1) * 130 + (xhi + 1)) * 32;
#pragma unroll
    for (int c = 0; c < 32; ++c) {
        float v = wylo * (wxlo * b2f(p00[c]) + wxhi * b2f(p01[c]))
                + wyhi * (wxlo * b2f(p10[c]) + wxhi * b2f(p11[c]));
        dst[c] = f2b(v);
    }
}

// ---------------------------------------------------------------------------
// Final 9-tap dilated gather; thread = (plane b*2+cc, pixel), 32 channels.
// up is pad-2 chunked bf16 -> all taps in-bounds (borders are zero).
// ---------------------------------------------------------------------------
__global__ __launch_bounds__(256)
void fuse_apply_c(const float* __restrict__ fuse, const ushort* __restrict__ up,
                  float* __restrict__ out) {
    int p = blockIdx.x * 256 + threadIdx.x;     // pixel within batch image
    int pl = blockIdx.y;
    int b = pl >> 1, cc = pl & 1;
    int y = p >> 8, x = p & 255;

    const float* f = fuse + (size_t)b * 9 * HW2 + p;
    const ushort* ub = up + (size_t)pl * 260 * 260 * 32;

    float acc[32];
#pragma unroll
    for (int c = 0; c < 32; ++c) acc[c] = 0.f;
#pragma unroll
    for (int t = 0; t < 9; ++t) {
        int dy = (t / 3 - 1) * 2, dx = (t % 3 - 1) * 2;
        float fv = f[(size_t)t * HW2];
        const ushort* u = ub + ((size_t)(y + 2 + dy) * 260 + (x + 2 + dx)) * 32;
#pragma unroll
        for (int c = 0; c < 32; ++c) acc[c] = fmaf(fv, b2f(u[c]), acc[c]);
    }
    float* ob = out + ((size_t)(b * 64 + cc * 32)) * HW2 + p;
#pragma unroll
    for (int c = 0; c < 32; ++c) ob[(size_t)c * HW2] = acc[c];
}

// ---------------------------------------------------------------------------
extern "C" void kernel_launch(void* const* d_in, const int* in_sizes, int n_in,
                              void* d_out, int out_size, void* d_ws, size_t ws_size,
                              hipStream_t stream) {
    const float* depth  = (const float*)d_in[0];
    const float* guide  = (const float*)d_in[1];
    const float* inputs = (const float*)d_in[2];
    const float* dk_w1  = (const float*)d_in[3];
    const float* dk_b1  = (const float*)d_in[4];
    const float* dk_w2  = (const float*)d_in[5];
    const float* dk_b2  = (const float*)d_in[6];
    const float* gk_w1  = (const float*)d_in[7];
    const float* gk_b1  = (const float*)d_in[8];
    const float* gk_w2  = (const float*)d_in[9];
    const float* gk_b2  = (const float*)d_in[10];
    const float* wn_w1  = (const float*)d_in[11];
    const float* wn_b1  = (const float*)d_in[12];
    const float* wn_w2  = (const float*)d_in[13];
    const float* wn_b2  = (const float*)d_in[14];
    const float* wn_w3  = (const float*)d_in[15];
    const float* wn_b3  = (const float*)d_in[16];
    const float* rb_w   = (const float*)d_in[17];
    const float* rb_b   = (const float*)d_in[18];
    const float* aff    = (const float*)d_in[19];
    float* out = (float*)d_out;

    // ---- workspace layout (float units; all chunked bufs are ushort) ----
    float* ws = (float*)d_ws;
    size_t off = 0;
    const size_t CH256 = 4260096;   // 4 planes * 258*258*32 ushorts / 2
    const size_t CH128 = 1081600;   // 4 planes * 130*130*32 ushorts / 2
    ushort* depth_c = (ushort*)(ws + off); off += CH256;
    ushort* guide_c = (ushort*)(ws + off); off += CH256;
    ushort* bufA    = (ushort*)(ws + off); off += CH256;   // wn1 out; later aliased by `up`
    ushort* bufB    = (ushort*)(ws + off); off += CH256;   // wn2 out
    ushort* up      = bufA;                                 // 4*260*260*32 ushorts fits in bufA+bufB
    ushort* inp_c   = (ushort*)(ws + off); off += CH128;
    ushort* r0      = (ushort*)(ws + off); off += CH128;
    ushort* r1      = (ushort*)(ws + off); off += CH128;
    ushort* r2      = (ushort*)(ws + off); off += CH128;
    float* fuse     = ws + off; off += 1179648;
    float* wmap     = ws + off; off += 131072;
    ushort* wt_wn1  = (ushort*)(ws + off); off += 36864;
    ushort* wt_wn2  = (ushort*)(ws + off); off += 18432;
    ushort* wt_rb   = (ushort*)(ws + off); off += 73728;

    // ---- weight repack (bf16, [cc][t][co][ci32]) ----
    repack_w_bf16<<<288, 256, 0, stream>>>(wn_w1, wt_wn1, 128);
    repack_w_bf16<<<144, 256, 0, stream>>>(wn_w2, wt_wn2, 64);
    for (int s = 0; s < 4; ++s)
        repack_w_bf16<<<144, 256, 0, stream>>>(rb_w + s * 36864, wt_rb + (size_t)s * 36864, 64);

    // ---- activation layout conversion (fp32 NCHW -> padded chunked bf16) ----
    to_chunked<<<dim3(261, 4), 256, 0, stream>>>(depth,  depth_c, 256, 256, 2);
    to_chunked<<<dim3(261, 4), 256, 0, stream>>>(guide,  guide_c, 256, 256, 2);
    to_chunked<<<dim3(67,  4), 256, 0, stream>>>(inputs, inp_c,   128, 128, 2);

    // ---- zero borders of conv-output buffers (bufA+bufB, r0+r1 contiguous) ----
    zero_border<<<17, 256, 0, stream>>>(bufA, 256, 256, 8);
    zero_border<<<9,  256, 0, stream>>>(r0,   128, 128, 8);

    // ---- weight-map trunk ----
    conv3x3_reg<4, true, false, true ><<<dim3(16, 16, 2), 256, 0, stream>>>(
        depth_c, guide_c, wt_wn1, wn_b1, nullptr, bufA, 256, 256);
    conv3x3_reg<2, true, false, false><<<dim3(16, 16, 2), 256, 0, stream>>>(
        bufA, nullptr, wt_wn2, wn_b2, nullptr, bufB, 256, 256);
    conv3x3_1out_c<<<dim3(16, 16, 2), 256, 0, stream>>>(bufB, wn_w3, wn_b3, wmap);

    // ---- dk/gk branches + blend + tanh + normalize ----
    kernels_fuse_c<<<512, 256, 0, stream>>>(depth_c, guide_c, wmap,
                                            dk_w1, dk_b1, dk_w2, dk_b2,
                                            gk_w1, gk_b1, gk_w2, gk_b2,
                                            aff, fuse);

    // ---- residual stack (128x128), 2-wave blocks for CU coverage ----
    conv3x3_reg<2, true,  false, false><<<dim3(8, 16, 2), 128, 0, stream>>>(
        inp_c, nullptr, wt_rb + 0 * 36864, rb_b + 0 * 64, nullptr, r0, 128, 128);
    conv3x3_reg<2, false, true,  false><<<dim3(8, 16, 2), 128, 0, stream>>>(
        r0, nullptr, wt_rb + 1 * 36864, rb_b + 1 * 64, inp_c, r1, 128, 128);
    conv3x3_reg<2, true,  false, false><<<dim3(8, 16, 2), 128, 0, stream>>>(
        r1, nullptr, wt_rb + 2 * 36864, rb_b + 2 * 64, nullptr, r0, 128, 128);
    conv3x3_reg<2, false, true,  false><<<dim3(8, 16, 2), 128, 0, stream>>>(
        r0, nullptr, wt_rb + 3 * 36864, rb_b + 3 * 64, r1, r2, 128, 128);

    // ---- upsample (writes own pad-2 borders) + 9-tap dilated gather ----
    upsample2x_c<<<dim3(265, 4), 256, 0, stream>>>(r2, up);
    fuse_apply_c<<<dim3(256, 4), 256, 0, stream>>>(fuse, up, out);
}

// Round 4
// 350.207 us; speedup vs baseline: 3.5001x; 1.2908x over previous
//
#include <hip/hip_runtime.h>
#include <hip/hip_bf16.h>
#include <math.h>

#define HW2 (256*256)
#define HW1 (128*128)

typedef __attribute__((ext_vector_type(8))) short short8;
typedef __attribute__((ext_vector_type(4))) float floatx4;

__device__ __forceinline__ float b2f(ushort u) {
    union { unsigned int i; float f; } v; v.i = ((unsigned int)u) << 16; return v.f;
}
__device__ __forceinline__ ushort f2b(float f) {
    __hip_bfloat16 h = __float2bfloat16(f); return *(ushort*)&h;
}

// ---------------------------------------------------------------------------
// Repack conv weights OIHW fp32 (Cout=64, Cin, 3,3) -> bf16 [ci/32][t][co][ci%32]
// ---------------------------------------------------------------------------
__global__ __launch_bounds__(256)
void repack_w_bf16(const float* __restrict__ w, ushort* __restrict__ wt, int Cin) {
    int idx = blockIdx.x * 256 + threadIdx.x;
    int total = 64 * Cin * 9;
    if (idx >= total) return;
    int o   = idx / (Cin * 9);
    int rem = idx - o * (Cin * 9);
    int ci  = rem / 9;
    int t   = rem - ci * 9;
    int cc = ci >> 5, cl = ci & 31;
    wt[(((size_t)cc * 9 + t) * 64 + o) * 32 + cl] = f2b(w[idx]);
}

// Batched version for the five Cin=64 weight sets (wn2, rb0..3).
__global__ __launch_bounds__(256)
void repack_w64_batched(const float* __restrict__ wn_w2, const float* __restrict__ rb_w,
                        ushort* __restrict__ wt_wn2, ushort* __restrict__ wt_rb) {
    int idx = blockIdx.x * 256 + threadIdx.x;
    if (idx >= 36864) return;
    int set = blockIdx.y;
    const float* w = (set == 0) ? wn_w2 : rb_w + (size_t)(set - 1) * 36864;
    ushort* wt     = (set == 0) ? wt_wn2 : wt_rb + (size_t)(set - 1) * 36864;
    int o   = idx / 576;
    int rem = idx - o * 576;
    int ci  = rem / 9;
    int t   = rem - ci * 9;
    int cc = ci >> 5, cl = ci & 31;
    wt[(((size_t)cc * 9 + t) * 64 + o) * 32 + cl] = f2b(w[idx]);
}

// 1x1 weights -> bf16 row-major; w2 sets padded to 16 rows with zeros.
// set 0: dk_w1 (64x64), 1: gk_w1 (64x64), 2: dk_w2 (9x64 ->16x64), 3: gk_w2
__global__ __launch_bounds__(256)
void repack_1x1(const float* __restrict__ dk_w1, const float* __restrict__ gk_w1,
                const float* __restrict__ dk_w2, const float* __restrict__ gk_w2,
                ushort* __restrict__ w1d, ushort* __restrict__ w1g,
                ushort* __restrict__ w2d, ushort* __restrict__ w2g) {
    int idx = blockIdx.x * 256 + threadIdx.x;
    int set = blockIdx.y;
    if (set < 2) {
        if (idx >= 4096) return;
        const float* s = set == 0 ? dk_w1 : gk_w1;
        ushort* d = set == 0 ? w1d : w1g;
        d[idx] = f2b(s[idx]);
    } else {
        if (idx >= 1024) return;
        const float* s = set == 2 ? dk_w2 : gk_w2;
        ushort* d = set == 2 ? w2d : w2g;
        int row = idx >> 6;
        d[idx] = (row < 9) ? f2b(s[idx]) : (ushort)0;
    }
}

// ---------------------------------------------------------------------------
// NCHW fp32 -> border-padded channel-chunked bf16: [plane][(H+2)][(W+2)][32]
// ---------------------------------------------------------------------------
__global__ __launch_bounds__(256)
void to_chunked(const float* __restrict__ in, ushort* __restrict__ outc,
                int H, int W, int Cchunks) {
    int P = W + 2, Q = H + 2;
    int plane_px = P * Q;
    int idx = blockIdx.x * 256 + threadIdx.x;
    if (idx >= plane_px) return;
    int py = idx / P, px = idx - py * P;
    int bc = blockIdx.y;
    int b = bc / Cchunks, cc = bc - b * Cchunks;
    ushort* dst = outc + ((size_t)bc * plane_px + idx) * 32;
    if (py == 0 || py == Q - 1 || px == 0 || px == P - 1) {
        for (int c = 0; c < 32; ++c) dst[c] = 0;
        return;
    }
    int y = py - 1, x = px - 1;
    const float* src = in + ((size_t)b * (Cchunks * 32) + cc * 32) * H * W
                          + (size_t)y * W + x;
    for (int c = 0; c < 32; ++c)
        dst[c] = f2b(src[(size_t)c * H * W]);
}

// Merged depth+guide conversion (256x256): planes 0-3 depth, 4-7 guide;
// depth_c and guide_c are contiguous in ws.
__global__ __launch_bounds__(256)
void to_chunked_hi(const float* __restrict__ depth, const float* __restrict__ guide,
                   ushort* __restrict__ outc) {
    const int P = 258;
    int plane_px = P * P;
    int idx = blockIdx.x * 256 + threadIdx.x;
    if (idx >= plane_px) return;
    int py = idx / P, px = idx - py * P;
    int pl = blockIdx.y;                 // 0..7
    const float* srcb = (pl < 4) ? depth : guide;
    int bc = pl & 3;
    int b = bc >> 1, cc = bc & 1;
    ushort* dst = outc + ((size_t)pl * plane_px + idx) * 32;
    if (py == 0 || py == P - 1 || px == 0 || px == P - 1) {
        for (int c = 0; c < 32; ++c) dst[c] = 0;
        return;
    }
    int y = py - 1, x = px - 1;
    const float* src = srcb + ((size_t)b * 64 + cc * 32) * HW2 + (size_t)y * 256 + x;
    for (int c = 0; c < 32; ++c)
        dst[c] = f2b(src[(size_t)c * HW2]);
}

// ---------------------------------------------------------------------------
// Zero 1-px borders of nplanes chunked planes.
// ---------------------------------------------------------------------------
__global__ __launch_bounds__(256)
void zero_border(ushort* __restrict__ buf, int H, int W, int nplanes) {
    int P = W + 2, Q = H + 2;
    int nb = 2 * P + 2 * H;
    int idx = blockIdx.x * 256 + threadIdx.x;
    if (idx >= nb * nplanes) return;
    int pl = idx / nb, r = idx - pl * nb;
    int py, px;
    if (r < P)          { py = 0;     px = r; }
    else if (r < 2 * P) { py = Q - 1; px = r - P; }
    else { int k = r - 2 * P; py = 1 + (k >> 1); px = (k & 1) ? P - 1 : 0; }
    ushort* dst = buf + ((size_t)pl * P * Q + (size_t)py * P + px) * 32;
    for (int c = 0; c < 32; ++c) dst[c] = 0;
}

// ---------------------------------------------------------------------------
// LDS-free, barrier-free implicit-GEMM conv3x3 (pad=1), Cout=64.
// ---------------------------------------------------------------------------
template<int NCHUNK, bool RELU, bool HAS_SKIP, bool CONCAT2>
__global__ __launch_bounds__(256)
void conv3x3_reg(const ushort* __restrict__ inA, const ushort* __restrict__ inB,
                 const ushort* __restrict__ wt, const float* __restrict__ bias,
                 const ushort* __restrict__ skip, ushort* __restrict__ outc,
                 int H, int W) {
    const int P = W + 2;
    const size_t plane = (size_t)P * (H + 2) * 32;
    int tid = threadIdx.x;
    int wv = tid >> 6, lane = tid & 63, ml = lane & 15, q = lane >> 4;
    int x0 = blockIdx.x * 16;
    int rowsPerBlock = (blockDim.x >> 6) * 4;
    int yb = blockIdx.y * rowsPerBlock + wv * 4;
    int b = blockIdx.z;

    floatx4 acc[4][4];
#pragma unroll
    for (int r = 0; r < 4; ++r)
#pragma unroll
        for (int n = 0; n < 4; ++n) acc[r][n] = (floatx4){0.f, 0.f, 0.f, 0.f};

    for (int cc = 0; cc < NCHUNK; ++cc) {
        const ushort* base;
        if (CONCAT2) {
            constexpr int HC = NCHUNK / 2;
            if (cc < HC) base = inA + ((size_t)(b * HC + cc)) * plane;
            else         base = inB + ((size_t)(b * HC + cc - HC)) * plane;
        } else {
            base = inA + ((size_t)(b * NCHUNK + cc)) * plane;
        }
        const ushort* wb = wt + (size_t)cc * 18432;
#pragma unroll
        for (int t = 0; t < 9; ++t) {
            int dy = t / 3, dx = t - 3 * dy;
            short8 afr[4], bfr[4];
#pragma unroll
            for (int r = 0; r < 4; ++r)
                afr[r] = *(const short8*)&base[((size_t)(yb + r + dy) * P
                                               + (x0 + ml + dx)) * 32 + q * 8];
#pragma unroll
            for (int n = 0; n < 4; ++n)
                bfr[n] = *(const short8*)&wb[(size_t)(t * 64 + n * 16 + ml) * 32 + q * 8];
#pragma unroll
            for (int r = 0; r < 4; ++r)
#pragma unroll
                for (int n = 0; n < 4; ++n)
                    acc[r][n] = __builtin_amdgcn_mfma_f32_16x16x32_bf16(
                        afr[r], bfr[n], acc[r][n], 0, 0, 0);
        }
    }

#pragma unroll
    for (int r = 0; r < 4; ++r) {
        int y = yb + r;
#pragma unroll
        for (int n = 0; n < 4; ++n) {
            int ch = n * 16 + ml;
            int occ = ch >> 5, ocl = ch & 31;
            float bs = bias[ch];
            size_t pbase = ((size_t)(b * 2 + occ)) * plane + ((size_t)(y + 1) * P) * 32 + ocl;
#pragma unroll
            for (int e = 0; e < 4; ++e) {
                int x = x0 + q * 4 + e;
                float v = acc[r][n][e] + bs;
                if (RELU) v = fmaxf(v, 0.f);
                if (HAS_SKIP)
                    v += b2f(skip[((size_t)(b * 2 + occ)) * plane
                                  + ((size_t)(y + 1) * P + (x + 1)) * 32 + ocl]);
                outc[pbase + (size_t)(x + 1) * 32] = f2b(v);
            }
        }
    }
}

// ---------------------------------------------------------------------------
// wn3: 3x3 conv 64ch -> 1ch at 256x256 from chunked bf16 input.
// ---------------------------------------------------------------------------
__global__ __launch_bounds__(256)
void conv3x3_1out_c(const ushort* __restrict__ inc, const float* __restrict__ w,
                    const float* __restrict__ bias, float* __restrict__ out) {
    __shared__ float wl[576];
    int tid = threadIdx.x;
    for (int i = tid; i < 576; i += 256) wl[i] = w[i];
    __syncthreads();

    int x = blockIdx.x * 16 + (tid & 15);
    int y = blockIdx.y * 16 + (tid >> 4);
    int b = blockIdx.z;
    const int P = 258;
    const size_t plane = (size_t)P * 258 * 32;

    float acc = bias[0];
    for (int cc = 0; cc < 2; ++cc) {
        const ushort* base = inc + ((size_t)(b * 2 + cc)) * plane;
#pragma unroll
        for (int t = 0; t < 9; ++t) {
            int dy = t / 3, dx = t - 3 * dy;
            const ushort* p = base + ((size_t)(y + dy) * P + (x + dx)) * 32;
            for (int c = 0; c < 32; ++c)
                acc = fmaf(wl[(cc * 32 + c) * 9 + t], b2f(p[c]), acc);
        }
    }
    out[(size_t)b * HW2 + y * 256 + x] = acc;
}

// ---------------------------------------------------------------------------
// MFMA dk/gk branches + softmax + blend + tanh + L1-norm.
// Wave owns 16 pixels. GEMM1: [16px x 64hid, K=64] -> ReLU -> LDS transpose
// -> GEMM2 (out^T: [16j x 16px, K=64]). Softmax over j via 2 shfl_xor.
// ---------------------------------------------------------------------------
__global__ __launch_bounds__(256)
void kernels_fuse_mfma(const ushort* __restrict__ depth_c, const ushort* __restrict__ guide_c,
                       const float* __restrict__ wmap,
                       const ushort* __restrict__ w1d, const float* __restrict__ b1d,
                       const ushort* __restrict__ w2d, const float* __restrict__ b2d,
                       const ushort* __restrict__ w1g, const float* __restrict__ b1g,
                       const ushort* __restrict__ w2g, const float* __restrict__ b2g,
                       const float* __restrict__ aff, float* __restrict__ fuse_out) {
    __shared__ __align__(16) ushort hid[2][4][16 * 72];   // [branch][wave][px][hid]

    int tid = threadIdx.x;
    int wv = tid >> 6, lane = tid & 63, ml = lane & 15, q = lane >> 4;
    int p0 = blockIdx.x * 64 + wv * 16;
    int b = p0 >> 16, rem0 = p0 & 65535;
    const size_t plane = (size_t)258 * 258 * 32;

    // pixel owned by this lane (both as A-row index in GEMM1 and C-col in GEMM2)
    int rem = rem0 + ml;
    int y = rem >> 8, x = rem & 255;
    size_t poff = ((size_t)(y + 1) * 258 + (x + 1)) * 32;

    float sm[2][4];    // softmax-ed kernels, [branch][e], j = q*4+e

    for (int br = 0; br < 2; ++br) {
        const ushort* src = br ? guide_c : depth_c;
        const ushort* w1  = br ? w1g : w1d;
        const float*  b1  = br ? b1g : b1d;
        const ushort* w2  = br ? w2g : w2d;
        const float*  b2  = br ? b2g : b2d;
        ushort* h = hid[br][wv];

        // ---- GEMM1: hidden[px][h] ----
        short8 afr[2];
#pragma unroll
        for (int kc = 0; kc < 2; ++kc)
            afr[kc] = *(const short8*)&src[(size_t)(b * 2 + kc) * plane + poff + q * 8];

        floatx4 acc[4];
#pragma unroll
        for (int nt = 0; nt < 4; ++nt) acc[nt] = (floatx4){0.f, 0.f, 0.f, 0.f};
#pragma unroll
        for (int nt = 0; nt < 4; ++nt)
#pragma unroll
            for (int kc = 0; kc < 2; ++kc) {
                short8 bfr = *(const short8*)&w1[(size_t)((nt * 16 + ml) * 64 + kc * 32 + q * 8)];
                acc[nt] = __builtin_amdgcn_mfma_f32_16x16x32_bf16(afr[kc], bfr, acc[nt], 0, 0, 0);
            }

        // bias + ReLU, transpose into LDS as bf16 [px][hid] (stride 72)
#pragma unroll
        for (int nt = 0; nt < 4; ++nt) {
            float bs = b1[nt * 16 + ml];
#pragma unroll
            for (int e = 0; e < 4; ++e) {
                float v = acc[nt][e] + bs;
                v = fmaxf(v, 0.f);
                h[(q * 4 + e) * 72 + nt * 16 + ml] = f2b(v);
            }
        }
        __syncthreads();

        // ---- GEMM2: out^T[j][px], A = w2 (16x64 row-major), B = hidden ----
        floatx4 d2 = (floatx4){0.f, 0.f, 0.f, 0.f};
#pragma unroll
        for (int kc = 0; kc < 2; ++kc) {
            short8 a2 = *(const short8*)&w2[(size_t)(ml * 64 + kc * 32 + q * 8)];
            short8 hf = *(const short8*)&h[ml * 72 + kc * 32 + q * 8];
            d2 = __builtin_amdgcn_mfma_f32_16x16x32_bf16(a2, hf, d2, 0, 0, 0);
        }

        // logits: j = q*4+e; invalid rows -> -inf
        float lg[4];
#pragma unroll
        for (int e = 0; e < 4; ++e) {
            int j = q * 4 + e;
            lg[e] = (j < 9) ? (d2[e] + b2[j]) : -1e30f;
        }
        // softmax over j (across q-lanes, pixel = ml fixed)
        float m = fmaxf(fmaxf(lg[0], lg[1]), fmaxf(lg[2], lg[3]));
        m = fmaxf(m, __shfl_xor(m, 16));
        m = fmaxf(m, __shfl_xor(m, 32));
        float s = 0.f;
#pragma unroll
        for (int e = 0; e < 4; ++e) { lg[e] = __expf(lg[e] - m); s += lg[e]; }
        s += __shfl_xor(s, 16);
        s += __shfl_xor(s, 32);
        float inv = 1.f / s;
#pragma unroll
        for (int e = 0; e < 4; ++e) sm[br][e] = lg[e] * inv;
    }

    // ---- blend + tanh + L1-normalize + store ----
    float wm = wmap[p0 + ml];
    float inv_av = 1.f / (aff[0] + 1e-8f);
    float f[4];
    float s = 0.f;
#pragma unroll
    for (int e = 0; e < 4; ++e) {
        float v = wm * sm[0][e] + (1.f - wm) * sm[1][e];
        v = tanhf(v) * inv_av;
        f[e] = v;
        s += fabsf(v);
    }
    s += __shfl_xor(s, 16);
    s += __shfl_xor(s, 32);
    float ksum = s + 1e-4f;
    if (ksum < 1.f) ksum = 1.f;
    float invk = 1.f / ksum;
#pragma unroll
    for (int e = 0; e < 4; ++e) {
        int j = q * 4 + e;
        if (j < 9)
            fuse_out[((size_t)b * 9 + j) * HW2 + rem0 + ml] = f[e] * invk;
    }
}

// ---------------------------------------------------------------------------
// Bilinear 2x upsample: chunked bf16 (130-pad1) -> chunked bf16 (260-pad2).
// ---------------------------------------------------------------------------
__global__ __launch_bounds__(256)
void upsample2x_c(const ushort* __restrict__ inc, ushort* __restrict__ outc) {
    int idx = blockIdx.x * 256 + threadIdx.x;
    if (idx >= 260 * 260) return;
    int py = idx / 260, px = idx - py * 260;
    int pl = blockIdx.y;
    ushort* dst = outc + ((size_t)pl * 260 * 260 + idx) * 32;
    if (py < 2 || py >= 258 || px < 2 || px >= 258) {
        for (int c = 0; c < 32; ++c) dst[c] = 0;
        return;
    }
    int y = py - 2, x = px - 2;

    int ylo, yhi; float wylo, wyhi;
    if (y & 1) { ylo = y >> 1; yhi = ylo + 1; if (yhi > 127) yhi = 127; wylo = 0.75f; wyhi = 0.25f; }
    else       { yhi = y >> 1; ylo = yhi - 1; if (ylo < 0)   ylo = 0;   wyhi = 0.75f; wylo = 0.25f; }
    int xlo, xhi; float wxlo, wxhi;
    if (x & 1) { xlo = x >> 1; xhi = xlo + 1; if (xhi > 127) xhi = 127; wxlo = 0.75f; wxhi = 0.25f; }
    else       { xhi = x >> 1; xlo = xhi - 1; if (xlo < 0)   xlo = 0;   wxhi = 0.75f; wxlo = 0.25f; }

    const ushort* base = inc + (size_t)pl * 130 * 130 * 32;
    const ushort* p00 = base + ((size_t)(ylo + 1) * 130 + (xlo + 1)) * 32;
    const ushort* p01 = base + ((size_t)(ylo + 1) * 130 + (xhi + 1)) * 32;
    const ushort* p10 = base + ((size_t)(yhi + 1) * 130 + (xlo + 1)) * 32;
    const ushort* p11 = base + ((size_t)(yhi + 1) * 130 + (xhi + 1)) * 32;
#pragma unroll
    for (int c = 0; c < 32; ++c) {
        float v = wylo * (wxlo * b2f(p00[c]) + wxhi * b2f(p01[c]))
                + wyhi * (wxlo * b2f(p10[c]) + wxhi * b2f(p11[c]));
        dst[c] = f2b(v);
    }
}

// ---------------------------------------------------------------------------
// Final 9-tap dilated gather.
// ---------------------------------------------------------------------------
__global__ __launch_bounds__(256)
void fuse_apply_c(const float* __restrict__ fuse, const ushort* __restrict__ up,
                  float* __restrict__ out) {
    int p = blockIdx.x * 256 + threadIdx.x;
    int pl = blockIdx.y;
    int b = pl >> 1, cc = pl & 1;
    int y = p >> 8, x = p & 255;

    const float* f = fuse + (size_t)b * 9 * HW2 + p;
    const ushort* ub = up + (size_t)pl * 260 * 260 * 32;

    float acc[32];
#pragma unroll
    for (int c = 0; c < 32; ++c) acc[c] = 0.f;
#pragma unroll
    for (int t = 0; t < 9; ++t) {
        int dy = (t / 3 - 1) * 2, dx = (t % 3 - 1) * 2;
        float fv = f[(size_t)t * HW2];
        const ushort* u = ub + ((size_t)(y + 2 + dy) * 260 + (x + 2 + dx)) * 32;
#pragma unroll
        for (int c = 0; c < 32; ++c) acc[c] = fmaf(fv, b2f(u[c]), acc[c]);
    }
    float* ob = out + ((size_t)(b * 64 + cc * 32)) * HW2 + p;
#pragma unroll
    for (int c = 0; c < 32; ++c) ob[(size_t)c * HW2] = acc[c];
}

// ---------------------------------------------------------------------------
extern "C" void kernel_launch(void* const* d_in, const int* in_sizes, int n_in,
                              void* d_out, int out_size, void* d_ws, size_t ws_size,
                              hipStream_t stream) {
    const float* depth  = (const float*)d_in[0];
    const float* guide  = (const float*)d_in[1];
    const float* inputs = (const float*)d_in[2];
    const float* dk_w1  = (const float*)d_in[3];
    const float* dk_b1  = (const float*)d_in[4];
    const float* dk_w2  = (const float*)d_in[5];
    const float* dk_b2  = (const float*)d_in[6];
    const float* gk_w1  = (const float*)d_in[7];
    const float* gk_b1  = (const float*)d_in[8];
    const float* gk_w2  = (const float*)d_in[9];
    const float* gk_b2  = (const float*)d_in[10];
    const float* wn_w1  = (const float*)d_in[11];
    const float* wn_b1  = (const float*)d_in[12];
    const float* wn_w2  = (const float*)d_in[13];
    const float* wn_b2  = (const float*)d_in[14];
    const float* wn_w3  = (const float*)d_in[15];
    const float* wn_b3  = (const float*)d_in[16];
    const float* rb_w   = (const float*)d_in[17];
    const float* rb_b   = (const float*)d_in[18];
    const float* aff    = (const float*)d_in[19];
    float* out = (float*)d_out;

    // ---- workspace layout (float units) ----
    float* ws = (float*)d_ws;
    size_t off = 0;
    const size_t CH256 = 4260096;   // 4 planes * 258*258*32 ushorts / 2
    const size_t CH128 = 1081600;
    ushort* depth_c = (ushort*)(ws + off); off += CH256;   // depth_c+guide_c contiguous
    ushort* guide_c = (ushort*)(ws + off); off += CH256;
    ushort* bufA    = (ushort*)(ws + off); off += CH256;
    ushort* bufB    = (ushort*)(ws + off); off += CH256;
    ushort* up      = bufA;
    ushort* inp_c   = (ushort*)(ws + off); off += CH128;
    ushort* r0      = (ushort*)(ws + off); off += CH128;
    ushort* r1      = (ushort*)(ws + off); off += CH128;
    ushort* r2      = (ushort*)(ws + off); off += CH128;
    float* fuse     = ws + off; off += 1179648;
    float* wmap     = ws + off; off += 131072;
    ushort* wt_wn1  = (ushort*)(ws + off); off += 36864;
    ushort* wt_wn2  = (ushort*)(ws + off); off += 18432;
    ushort* wt_rb   = (ushort*)(ws + off); off += 73728;
    ushort* w1d_b   = (ushort*)(ws + off); off += 2048;    // 4096 bf16
    ushort* w1g_b   = (ushort*)(ws + off); off += 2048;
    ushort* w2d_b   = (ushort*)(ws + off); off += 512;     // 16x64 bf16
    ushort* w2g_b   = (ushort*)(ws + off); off += 512;

    // ---- weight repacks (3 dispatches) ----
    repack_w_bf16<<<288, 256, 0, stream>>>(wn_w1, wt_wn1, 128);
    repack_w64_batched<<<dim3(144, 5), 256, 0, stream>>>(wn_w2, rb_w, wt_wn2, wt_rb);
    repack_1x1<<<dim3(16, 4), 256, 0, stream>>>(dk_w1, gk_w1, dk_w2, gk_w2,
                                                w1d_b, w1g_b, w2d_b, w2g_b);

    // ---- activation layout conversion ----
    to_chunked_hi<<<dim3(261, 8), 256, 0, stream>>>(depth, guide, depth_c);
    to_chunked<<<dim3(67, 4), 256, 0, stream>>>(inputs, inp_c, 128, 128, 2);

    // ---- zero borders of conv-output buffers ----
    zero_border<<<17, 256, 0, stream>>>(bufA, 256, 256, 8);
    zero_border<<<9,  256, 0, stream>>>(r0,   128, 128, 8);

    // ---- weight-map trunk ----
    conv3x3_reg<4, true, false, true ><<<dim3(16, 16, 2), 256, 0, stream>>>(
        depth_c, guide_c, wt_wn1, wn_b1, nullptr, bufA, 256, 256);
    conv3x3_reg<2, true, false, false><<<dim3(16, 16, 2), 256, 0, stream>>>(
        bufA, nullptr, wt_wn2, wn_b2, nullptr, bufB, 256, 256);
    conv3x3_1out_c<<<dim3(16, 16, 2), 256, 0, stream>>>(bufB, wn_w3, wn_b3, wmap);

    // ---- dk/gk branches + blend + tanh + normalize (MFMA) ----
    kernels_fuse_mfma<<<2048, 256, 0, stream>>>(depth_c, guide_c, wmap,
                                                w1d_b, dk_b1, w2d_b, dk_b2,
                                                w1g_b, gk_b1, w2g_b, gk_b2,
                                                aff, fuse);

    // ---- residual stack (128x128) ----
    conv3x3_reg<2, true,  false, false><<<dim3(8, 16, 2), 128, 0, stream>>>(
        inp_c, nullptr, wt_rb + 0 * 36864, rb_b + 0 * 64, nullptr, r0, 128, 128);
    conv3x3_reg<2, false, true,  false><<<dim3(8, 16, 2), 128, 0, stream>>>(
        r0, nullptr, wt_rb + 1 * 36864, rb_b + 1 * 64, inp_c, r1, 128, 128);
    conv3x3_reg<2, true,  false, false><<<dim3(8, 16, 2), 128, 0, stream>>>(
        r1, nullptr, wt_rb + 2 * 36864, rb_b + 2 * 64, nullptr, r0, 128, 128);
    conv3x3_reg<2, false, true,  false><<<dim3(8, 16, 2), 128, 0, stream>>>(
        r0, nullptr, wt_rb + 3 * 36864, rb_b + 3 * 64, r1, r2, 128, 128);

    // ---- upsample + 9-tap dilated gather ----
    upsample2x_c<<<dim3(265, 4), 256, 0, stream>>>(r2, up);
    fuse_apply_c<<<dim3(256, 4), 256, 0, stream>>>(fuse, up, out);
}